// Round 1
// baseline (19.048 us; speedup 1.0000x reference)
//
#include <hip/hip_runtime.h>
#include <hip/hip_bf16.h>
#include <math.h>

// SATNet forward on MI355X — dataflow-reduced form.
//
// Derivation (see round-0 analysis): the reference's sweeps update only
// V[:, :, 513:813] (aux columns), while the output reads V[:, :, 1:513]
// (input columns), which are written once from V_in and never modified.
// Hence G = S^T S, gdiag, and all NUM_SWEEPS x 300 scan steps are dead code.
//
// Output: t[b,j] = -V_in[b,:,j].v0 = cos(pi z)*(v0.v0) - sin(pi z)*(v0.P_j)
// with v0.v0 = 1 - O(1e-11) and v0.P_j = O(1e-11) (v0-component projected
// out before renormalization). So in real arithmetic:
//   zo = arccos(clip(cos(pi z), -1+1e-6, 1-1e-6)) / pi
//      = clamp(z, acos(1-1e-6)/pi, 1 - acos(1-1e-6)/pi)   for z in [0,1].
// We compute the trig round-trip explicitly (cheap; 8192 elements) to track
// the reference's endpoint behavior exactly.

__global__ void satnet_out_kernel(const float* __restrict__ x,
                                  float* __restrict__ out,
                                  int n) {
    int i = blockIdx.x * blockDim.x + threadIdx.x;
    if (i >= n) return;
    float z = x[i];
    // cos(pi*z): use cospif for correct argument reduction.
    float t = cospif(z);
    // clip(t, -1+1e-6, 1-1e-6)
    const float lo = -1.0f + 1e-6f;
    const float hi =  1.0f - 1e-6f;
    t = fminf(fmaxf(t, lo), hi);
    // arccos / pi
    out[i] = acosf(t) * 0.31830988618379067154f; // 1/pi
}

extern "C" void kernel_launch(void* const* d_in, const int* in_sizes, int n_in,
                              void* d_out, int out_size, void* d_ws, size_t ws_size,
                              hipStream_t stream) {
    const float* x = (const float*)d_in[0];   // (B, T, C) = (16,16,32) float32
    // d_in[1] = S (600x813), d_in[2] = v_rand (41x813): unused — dead in the
    // reference's output dataflow (sweeps only write aux columns; output reads
    // input columns).
    float* out = (float*)d_out;               // 8192 float32

    int n = out_size;                          // 8192
    int block = 256;
    int grid = (n + block - 1) / block;        // 32 blocks
    satnet_out_kernel<<<grid, block, 0, stream>>>(x, out, n);
}